// Round 1
// baseline (114.068 us; speedup 1.0000x reference)
//
#include <hip/hip_runtime.h>
#include <math.h>

#define N_SAMPLES 131072
#define HIDDEN    256
#define M_GRID    2048
#define REC       148          // floats per table record
#define U_LO      (-8.0f)
#define DELTA     0.0078125f   // 16 / 2048
#define INV_DELTA 128.0f

// Record layout (148 floats):
//   [0..16]   cw  (knot x positions, cw[0]=-5, cw[16]=5)
//   [17..19]  pad
//   for k in 0..15: base = 20 + 8k:
//     [base+0] ch[k]  [base+1] ch[k+1]  [base+2] dv[k]  [base+3] dv[k+1]
//     [base+4] lam[k] [base+5..7] pad
__device__ float g_H2[HIDDEN * M_GRID];     // 2 MB
__device__ float g_table[M_GRID * REC];     // 1.2 MB
__device__ float g_knots0[REC];

__device__ __forceinline__ float softplusf(float x) {
  return fmaxf(x, 0.0f) + log1pf(expf(-fabsf(x)));
}

// Process one 63-value raw-param column into a record.
__device__ void process_column(const float* __restrict__ raw, int stride,
                               float* __restrict__ rec) {
  float v[16];
  // ---- widths -> cw (written straight to rec[0..16]) ----
  float mx = -1e30f;
#pragma unroll
  for (int k = 0; k < 16; k++) { v[k] = raw[k * stride]; mx = fmaxf(mx, v[k]); }
  float s = 0.0f;
#pragma unroll
  for (int k = 0; k < 16; k++) { v[k] = expf(v[k] - mx); s += v[k]; }
  float scl = 0.984f / s;  // (1 - MIN_BIN*K) = 1 - 0.016
  rec[0] = -5.0f;
  float a = 0.0f;
#pragma unroll
  for (int k = 0; k < 16; k++) {
    a += fmaf(v[k], scl, 0.001f);
    rec[k + 1] = fmaf(a, 10.0f, -5.0f);
  }
  rec[16] = 5.0f;
  // ---- heights -> ch ----
  float ch[17];
  mx = -1e30f;
#pragma unroll
  for (int k = 0; k < 16; k++) { v[k] = raw[(16 + k) * stride]; mx = fmaxf(mx, v[k]); }
  s = 0.0f;
#pragma unroll
  for (int k = 0; k < 16; k++) { v[k] = expf(v[k] - mx); s += v[k]; }
  scl = 0.984f / s;
  ch[0] = -5.0f;
  a = 0.0f;
#pragma unroll
  for (int k = 0; k < 16; k++) {
    a += fmaf(v[k], scl, 0.001f);
    ch[k + 1] = fmaf(a, 10.0f, -5.0f);
  }
  ch[16] = 5.0f;
  // ---- derivatives (boundary = 1) ----
  float dv[17];
  dv[0] = 1.0f; dv[16] = 1.0f;
#pragma unroll
  for (int j = 0; j < 15; j++) dv[j + 1] = 0.001f + softplusf(raw[(32 + j) * stride]);
  // ---- lambdas ----
  float lm[16];
#pragma unroll
  for (int k = 0; k < 16; k++) {
    float xx = raw[(47 + k) * stride];
    lm[k] = fmaf(0.95f, 1.0f / (1.0f + expf(-xx)), 0.025f);
  }
  rec[17] = 0.0f; rec[18] = 0.0f; rec[19] = 0.0f;
#pragma unroll
  for (int k = 0; k < 16; k++) {
    float* sl = rec + 20 + 8 * k;
    sl[0] = ch[k]; sl[1] = ch[k + 1]; sl[2] = dv[k]; sl[3] = dv[k + 1];
    sl[4] = lm[k]; sl[5] = 0.0f; sl[6] = 0.0f; sl[7] = 0.0f;
  }
}

// Monotonic linear-rational spline, one scalar, params already gathered.
__device__ __forceinline__ float spline_eval(float z, float xk, float xk1,
                                             float yk, float yk1,
                                             float dk, float dk1, float lam) {
  float xc = fminf(fmaxf(z, -5.0f), 5.0f);
  float wk = xk1 - xk;
  float hk = yk1 - yk;
  float wb = sqrtf(dk / dk1);
  float wc = fmaf(lam, dk, (1.0f - lam) * wb * dk1) * (wk / hk);
  float ya = yk;
  float yb = yk + hk;
  float yc = ((1.0f - lam) * ya + lam * wb * yb) / ((1.0f - lam) + lam * wb);
  float th = (xc - xk) / wk;
  bool left = th <= lam;
  float num = left ? fmaf(ya, lam - th, wc * yc * th)
                   : fmaf(wc * yc, 1.0f - th, wb * yb * (th - lam));
  float den = left ? fmaf(wc, th, lam - th)
                   : fmaf(wc, 1.0f - th, wb * (th - lam));
  float y = num / den;
  bool inside = (z >= -5.0f) && (z <= 5.0f);
  return inside ? y : z;
}

// ---------------- Layer-2 GEMM: H2[o][m] = relu(sum_k W2[o][k]*h_k(u_m) + b2[o])
// h_k(u) = relu(u*W1[k][0] + b1[k]) computed on the fly (layer-1 fused).
__global__ __launch_bounds__(256) void k_gemm2(const float* __restrict__ W1,
                                               const float* __restrict__ b1,
                                               const float* __restrict__ W2,
                                               const float* __restrict__ b2) {
  __shared__ float Wt[64][68];  // [k][o] (transposed tile of W2)
  __shared__ float Ht[64][68];  // [k][m]
  const int t = threadIdx.x;
  const int m0 = blockIdx.x * 64;
  const int o0 = blockIdx.y * 64;
  const int ty = t >> 4, tx = t & 15;
  float acc[4][4] = {};
  for (int kc = 0; kc < 256; kc += 64) {
    {
      const int o = t >> 2, seg = t & 3;
      const float* src = W2 + (size_t)(o0 + o) * 256 + kc + seg * 16;
#pragma unroll
      for (int q = 0; q < 4; q++) {
        float4 v = *(const float4*)(src + 4 * q);
        int k = seg * 16 + 4 * q;
        Wt[k + 0][o] = v.x; Wt[k + 1][o] = v.y;
        Wt[k + 2][o] = v.z; Wt[k + 3][o] = v.w;
      }
    }
    {
      const int k = t & 63, mseg = (t >> 6) * 16;
      const float w1v = W1[2 * (kc + k)];
      const float b1v = b1[kc + k];
#pragma unroll
      for (int q = 0; q < 16; q++) {
        const int m = mseg + q;
        float u = fmaf((float)(m0 + m), DELTA, U_LO);
        Ht[k][m] = fmaxf(fmaf(u, w1v, b1v), 0.0f);
      }
    }
    __syncthreads();
#pragma unroll
    for (int k = 0; k < 64; k++) {
      float4 av = *(const float4*)&Wt[k][ty * 4];
      float4 bv = *(const float4*)&Ht[k][tx * 4];
      acc[0][0] = fmaf(av.x, bv.x, acc[0][0]); acc[0][1] = fmaf(av.x, bv.y, acc[0][1]);
      acc[0][2] = fmaf(av.x, bv.z, acc[0][2]); acc[0][3] = fmaf(av.x, bv.w, acc[0][3]);
      acc[1][0] = fmaf(av.y, bv.x, acc[1][0]); acc[1][1] = fmaf(av.y, bv.y, acc[1][1]);
      acc[1][2] = fmaf(av.y, bv.z, acc[1][2]); acc[1][3] = fmaf(av.y, bv.w, acc[1][3]);
      acc[2][0] = fmaf(av.z, bv.x, acc[2][0]); acc[2][1] = fmaf(av.z, bv.y, acc[2][1]);
      acc[2][2] = fmaf(av.z, bv.z, acc[2][2]); acc[2][3] = fmaf(av.z, bv.w, acc[2][3]);
      acc[3][0] = fmaf(av.w, bv.x, acc[3][0]); acc[3][1] = fmaf(av.w, bv.y, acc[3][1]);
      acc[3][2] = fmaf(av.w, bv.z, acc[3][2]); acc[3][3] = fmaf(av.w, bv.w, acc[3][3]);
    }
    __syncthreads();
  }
#pragma unroll
  for (int ii = 0; ii < 4; ii++) {
    const int o = o0 + ty * 4 + ii;
    const float bias = b2[o];
    float4 r;
    r.x = fmaxf(acc[ii][0] + bias, 0.0f);
    r.y = fmaxf(acc[ii][1] + bias, 0.0f);
    r.z = fmaxf(acc[ii][2] + bias, 0.0f);
    r.w = fmaxf(acc[ii][3] + bias, 0.0f);
    *(float4*)&g_H2[(size_t)o * M_GRID + m0 + tx * 4] = r;
  }
}

// ---------------- Layer-3 GEMM (odd rows of W3) + param processing -> g_table
__global__ __launch_bounds__(256) void k_gemm3proc(const float* __restrict__ W3,
                                                   const float* __restrict__ b3) {
  __shared__ float Wt[64][68];
  __shared__ float Ht[64][68];
  __shared__ float raws[64][65];  // [p][m]
  const int t = threadIdx.x;
  const int m0 = blockIdx.x * 64;
  const int ty = t >> 4, tx = t & 15;
  float acc[4][4] = {};
  for (int kc = 0; kc < 256; kc += 64) {
    {
      const int p = t >> 2, seg = t & 3;
      const int row = (p < 63) ? (2 * p + 1) : 1;
      const float* src = W3 + (size_t)row * 256 + kc + seg * 16;
#pragma unroll
      for (int q = 0; q < 4; q++) {
        float4 v = *(const float4*)(src + 4 * q);
        int k = seg * 16 + 4 * q;
        Wt[k + 0][p] = v.x; Wt[k + 1][p] = v.y;
        Wt[k + 2][p] = v.z; Wt[k + 3][p] = v.w;
      }
    }
    {
      const int k = t & 63, mseg = (t >> 6) * 16;
      const float* src = g_H2 + (size_t)(kc + k) * M_GRID + m0 + mseg;
#pragma unroll
      for (int q = 0; q < 4; q++) {
        float4 v = *(const float4*)(src + 4 * q);
        *(float4*)&Ht[k][mseg + 4 * q] = v;
      }
    }
    __syncthreads();
#pragma unroll
    for (int k = 0; k < 64; k++) {
      float4 av = *(const float4*)&Wt[k][ty * 4];
      float4 bv = *(const float4*)&Ht[k][tx * 4];
      acc[0][0] = fmaf(av.x, bv.x, acc[0][0]); acc[0][1] = fmaf(av.x, bv.y, acc[0][1]);
      acc[0][2] = fmaf(av.x, bv.z, acc[0][2]); acc[0][3] = fmaf(av.x, bv.w, acc[0][3]);
      acc[1][0] = fmaf(av.y, bv.x, acc[1][0]); acc[1][1] = fmaf(av.y, bv.y, acc[1][1]);
      acc[1][2] = fmaf(av.y, bv.z, acc[1][2]); acc[1][3] = fmaf(av.y, bv.w, acc[1][3]);
      acc[2][0] = fmaf(av.z, bv.x, acc[2][0]); acc[2][1] = fmaf(av.z, bv.y, acc[2][1]);
      acc[2][2] = fmaf(av.z, bv.z, acc[2][2]); acc[2][3] = fmaf(av.z, bv.w, acc[2][3]);
      acc[3][0] = fmaf(av.w, bv.x, acc[3][0]); acc[3][1] = fmaf(av.w, bv.y, acc[3][1]);
      acc[3][2] = fmaf(av.w, bv.z, acc[3][2]); acc[3][3] = fmaf(av.w, bv.w, acc[3][3]);
    }
    __syncthreads();
  }
#pragma unroll
  for (int ii = 0; ii < 4; ii++) {
    const int p = ty * 4 + ii;
    const int bi = (p < 63) ? (2 * p + 1) : 1;
    const float bias = b3[bi];
    raws[p][tx * 4 + 0] = acc[ii][0] + bias;
    raws[p][tx * 4 + 1] = acc[ii][1] + bias;
    raws[p][tx * 4 + 2] = acc[ii][2] + bias;
    raws[p][tx * 4 + 3] = acc[ii][3] + bias;
  }
  __syncthreads();
  if (t < 64) process_column(&raws[0][t], 65, g_table + (size_t)(m0 + t) * REC);
  if (t == 64 && blockIdx.x == 0) process_column(b3, 2, g_knots0);  // dim-0 constant knots
}

// ---------------- Main flow kernel: 4 steps per sample
__global__ __launch_bounds__(256) void k_main(const float* __restrict__ x,
                                              float* __restrict__ out) {
  __shared__ float kn0[REC];
  for (int j = threadIdx.x; j < REC; j += 256) kn0[j] = g_knots0[j];
  __syncthreads();
  const int i = blockIdx.x * 256 + threadIdx.x;
  const float2 xv = ((const float2*)x)[i];
  float z0 = xv.x, z1 = xv.y;
  ((float2*)out)[i] = xv;  // step 0 = input
  for (int t = 0; t < 4; t++) {
    // ---- dim 1: table lookup keyed by u = current z0 ----
    float tt = (z0 - U_LO) * INV_DELTA;
    int i0 = (int)floorf(tt);
    i0 = min(max(i0, 0), M_GRID - 2);
    float f = fminf(fmaxf(tt - (float)i0, 0.0f), 1.0f);
    const float* r0 = g_table + (size_t)i0 * REC;
    const float* r1 = r0 + REC;
    float cwv[17];
#pragma unroll
    for (int q = 0; q < 4; q++) {
      float4 a = *(const float4*)(r0 + 4 * q);
      float4 b = *(const float4*)(r1 + 4 * q);
      cwv[4 * q + 0] = fmaf(f, b.x - a.x, a.x);
      cwv[4 * q + 1] = fmaf(f, b.y - a.y, a.y);
      cwv[4 * q + 2] = fmaf(f, b.z - a.z, a.z);
      cwv[4 * q + 3] = fmaf(f, b.w - a.w, a.w);
    }
    cwv[16] = fmaf(f, r1[16] - r0[16], r0[16]);
    float xc1 = fminf(fmaxf(z1, -5.0f), 5.0f);
    int k1 = -1;
    float xk = cwv[0], xk1 = cwv[16];
    bool seen = false;
#pragma unroll
    for (int j = 0; j < 16; j++) {
      bool c = xc1 >= cwv[j];
      k1 += c ? 1 : 0;
      xk = c ? cwv[j] : xk;
      bool ff = (!c) && (!seen);
      xk1 = ff ? cwv[j] : xk1;
      seen = seen || (!c);
    }
    const float* s0 = r0 + 20 + 8 * k1;
    const float* s1 = s0 + REC;
    float4 pa = *(const float4*)s0;
    float4 pb = *(const float4*)s1;
    float la = s0[4], lb = s1[4];
    float yk  = fmaf(f, pb.x - pa.x, pa.x);
    float yk1 = fmaf(f, pb.y - pa.y, pa.y);
    float dk  = fmaf(f, pb.z - pa.z, pa.z);
    float dk1 = fmaf(f, pb.w - pa.w, pa.w);
    float lam = fmaf(f, lb - la, la);
    float z1n = spline_eval(z1, xk, xk1, yk, yk1, dk, dk1, lam);
    // ---- dim 0: constant knots from LDS ----
    float xc0 = fminf(fmaxf(z0, -5.0f), 5.0f);
    int k0 = -1;
    float xk0 = kn0[0], xk01 = kn0[16];
    bool seen0 = false;
#pragma unroll
    for (int j = 0; j < 16; j++) {
      float cj = kn0[j];
      bool c = xc0 >= cj;
      k0 += c ? 1 : 0;
      xk0 = c ? cj : xk0;
      bool ff = (!c) && (!seen0);
      xk01 = ff ? cj : xk01;
      seen0 = seen0 || (!c);
    }
    const int sb = 20 + 8 * k0;
    float z0n = spline_eval(z0, xk0, xk01, kn0[sb], kn0[sb + 1],
                            kn0[sb + 2], kn0[sb + 3], kn0[sb + 4]);
    z0 = z0n; z1 = z1n;
    ((float2*)(out + (size_t)(t + 1) * (N_SAMPLES * 2)))[i] = make_float2(z0, z1);
  }
}

extern "C" void kernel_launch(void* const* d_in, const int* in_sizes, int n_in,
                              void* d_out, int out_size, void* d_ws, size_t ws_size,
                              hipStream_t stream) {
  const float* x  = (const float*)d_in[0];
  const float* W1 = (const float*)d_in[1];
  const float* b1 = (const float*)d_in[2];
  const float* W2 = (const float*)d_in[3];
  const float* b2 = (const float*)d_in[4];
  const float* W3 = (const float*)d_in[5];
  const float* b3 = (const float*)d_in[6];
  float* out = (float*)d_out;
  hipLaunchKernelGGL(k_gemm2, dim3(M_GRID / 64, 4), dim3(256), 0, stream, W1, b1, W2, b2);
  hipLaunchKernelGGL(k_gemm3proc, dim3(M_GRID / 64), dim3(256), 0, stream, W3, b3);
  hipLaunchKernelGGL(k_main, dim3(N_SAMPLES / 256), dim3(256), 0, stream, x, out);
}

// Round 2
// 113.206 us; speedup vs baseline: 1.0076x; 1.0076x over previous
//
#include <hip/hip_runtime.h>
#include <math.h>

#define N_SAMPLES 131072
#define HIDDEN    256
#define M_GRID    2048
#define REC       148          // floats per table record
#define U_LO      (-8.0f)
#define DELTA     0.0078125f   // 16 / 2048
#define INV_DELTA 128.0f

// Record layout (148 floats = 37 float4):
//   [0..16]   cw  (knot x positions, cw[0]=-5, cw[16]=5)
//   [17..19]  pad
//   for k in 0..15: base = 20 + 8k:
//     [base+0] ch[k]  [base+1] ch[k+1]  [base+2] dv[k]  [base+3] dv[k+1]
//     [base+4] lam[k] [base+5..7] pad
__device__ float g_H2[HIDDEN * M_GRID];     // 2 MB
__device__ float g_table[M_GRID * REC];     // 1.2 MB
__device__ float g_knots0[REC];

__device__ __forceinline__ float rcpf(float x) { return __builtin_amdgcn_rcpf(x); }

__device__ __forceinline__ float softplusf(float x) {
  return fmaxf(x, 0.0f) + log1pf(expf(-fabsf(x)));
}

// Process one 63-value raw-param column into a record (vectorized stores).
__device__ void process_column(const float* __restrict__ raw, int stride,
                               float* __restrict__ rec) {
  float v[16];
  float cw[17], ch[17], dv[17], lm[16];
  // ---- widths -> cw ----
  float mx = -1e30f;
#pragma unroll
  for (int k = 0; k < 16; k++) { v[k] = raw[k * stride]; mx = fmaxf(mx, v[k]); }
  float s = 0.0f;
#pragma unroll
  for (int k = 0; k < 16; k++) { v[k] = expf(v[k] - mx); s += v[k]; }
  float scl = 0.984f / s;  // (1 - MIN_BIN*K)
  cw[0] = -5.0f;
  float a = 0.0f;
#pragma unroll
  for (int k = 0; k < 16; k++) {
    a += fmaf(v[k], scl, 0.001f);
    cw[k + 1] = fmaf(a, 10.0f, -5.0f);
  }
  cw[16] = 5.0f;
  // ---- heights -> ch ----
  mx = -1e30f;
#pragma unroll
  for (int k = 0; k < 16; k++) { v[k] = raw[(16 + k) * stride]; mx = fmaxf(mx, v[k]); }
  s = 0.0f;
#pragma unroll
  for (int k = 0; k < 16; k++) { v[k] = expf(v[k] - mx); s += v[k]; }
  scl = 0.984f / s;
  ch[0] = -5.0f;
  a = 0.0f;
#pragma unroll
  for (int k = 0; k < 16; k++) {
    a += fmaf(v[k], scl, 0.001f);
    ch[k + 1] = fmaf(a, 10.0f, -5.0f);
  }
  ch[16] = 5.0f;
  // ---- derivatives (boundary = 1) ----
  dv[0] = 1.0f; dv[16] = 1.0f;
#pragma unroll
  for (int j = 0; j < 15; j++) dv[j + 1] = 0.001f + softplusf(raw[(32 + j) * stride]);
  // ---- lambdas ----
#pragma unroll
  for (int k = 0; k < 16; k++) {
    float xx = raw[(47 + k) * stride];
    lm[k] = fmaf(0.95f, 1.0f / (1.0f + expf(-xx)), 0.025f);
  }
  // ---- emit as 37 dwordx4 stores ----
  float4* r4 = (float4*)rec;
  r4[0] = make_float4(cw[0], cw[1], cw[2], cw[3]);
  r4[1] = make_float4(cw[4], cw[5], cw[6], cw[7]);
  r4[2] = make_float4(cw[8], cw[9], cw[10], cw[11]);
  r4[3] = make_float4(cw[12], cw[13], cw[14], cw[15]);
  r4[4] = make_float4(cw[16], 0.0f, 0.0f, 0.0f);
#pragma unroll
  for (int k = 0; k < 16; k++) {
    r4[5 + 2 * k] = make_float4(ch[k], ch[k + 1], dv[k], dv[k + 1]);
    r4[6 + 2 * k] = make_float4(lm[k], 0.0f, 0.0f, 0.0f);
  }
}

// Monotonic linear-rational spline (approx rcp/sqrt; tol 0.099 >> 1ulp).
__device__ __forceinline__ float spline_eval(float z, float xk, float xk1,
                                             float yk, float yk1,
                                             float dk, float dk1, float lam) {
  float xc = fminf(fmaxf(z, -5.0f), 5.0f);
  float wk = xk1 - xk;
  float hk = yk1 - yk;
  float wb = __builtin_amdgcn_sqrtf(dk * rcpf(dk1));
  float wc = fmaf(lam, dk, (1.0f - lam) * wb * dk1) * wk * rcpf(hk);
  float ya = yk;
  float yb = yk + hk;
  float yc = fmaf(lam * wb, yb, (1.0f - lam) * ya) * rcpf(fmaf(lam, wb, 1.0f - lam));
  float th = (xc - xk) * rcpf(wk);
  bool left = th <= lam;
  float num = left ? fmaf(ya, lam - th, wc * yc * th)
                   : fmaf(wc * yc, 1.0f - th, wb * yb * (th - lam));
  float den = left ? fmaf(wc, th, lam - th)
                   : fmaf(wc, 1.0f - th, wb * (th - lam));
  float y = num * rcpf(den);
  bool inside = (z >= -5.0f) && (z <= 5.0f);
  return inside ? y : z;
}

// ---------------- Layer-2 GEMM: H2[o][m] = relu(sum_k W2[o][k]*h_k(u_m) + b2[o])
__global__ __launch_bounds__(256) void k_gemm2(const float* __restrict__ W1,
                                               const float* __restrict__ b1,
                                               const float* __restrict__ W2,
                                               const float* __restrict__ b2) {
  __shared__ float Wt[64][68];  // [k][o]
  __shared__ float Ht[64][68];  // [k][m]
  const int t = threadIdx.x;
  const int m0 = blockIdx.x * 64;
  const int o0 = blockIdx.y * 64;
  const int ty = t >> 4, tx = t & 15;
  float acc[4][4] = {};
  for (int kc = 0; kc < 256; kc += 64) {
    {
      const int o = t >> 2, seg = t & 3;
      const float* src = W2 + (size_t)(o0 + o) * 256 + kc + seg * 16;
#pragma unroll
      for (int q = 0; q < 4; q++) {
        float4 v = *(const float4*)(src + 4 * q);
        int k = seg * 16 + 4 * q;
        Wt[k + 0][o] = v.x; Wt[k + 1][o] = v.y;
        Wt[k + 2][o] = v.z; Wt[k + 3][o] = v.w;
      }
    }
    {
      const int k = t & 63, mseg = (t >> 6) * 16;
      const float w1v = W1[2 * (kc + k)];
      const float b1v = b1[kc + k];
#pragma unroll
      for (int q = 0; q < 16; q++) {
        const int m = mseg + q;
        float u = fmaf((float)(m0 + m), DELTA, U_LO);
        Ht[k][m] = fmaxf(fmaf(u, w1v, b1v), 0.0f);
      }
    }
    __syncthreads();
#pragma unroll
    for (int k = 0; k < 64; k++) {
      float4 av = *(const float4*)&Wt[k][ty * 4];
      float4 bv = *(const float4*)&Ht[k][tx * 4];
      acc[0][0] = fmaf(av.x, bv.x, acc[0][0]); acc[0][1] = fmaf(av.x, bv.y, acc[0][1]);
      acc[0][2] = fmaf(av.x, bv.z, acc[0][2]); acc[0][3] = fmaf(av.x, bv.w, acc[0][3]);
      acc[1][0] = fmaf(av.y, bv.x, acc[1][0]); acc[1][1] = fmaf(av.y, bv.y, acc[1][1]);
      acc[1][2] = fmaf(av.y, bv.z, acc[1][2]); acc[1][3] = fmaf(av.y, bv.w, acc[1][3]);
      acc[2][0] = fmaf(av.z, bv.x, acc[2][0]); acc[2][1] = fmaf(av.z, bv.y, acc[2][1]);
      acc[2][2] = fmaf(av.z, bv.z, acc[2][2]); acc[2][3] = fmaf(av.z, bv.w, acc[2][3]);
      acc[3][0] = fmaf(av.w, bv.x, acc[3][0]); acc[3][1] = fmaf(av.w, bv.y, acc[3][1]);
      acc[3][2] = fmaf(av.w, bv.z, acc[3][2]); acc[3][3] = fmaf(av.w, bv.w, acc[3][3]);
    }
    __syncthreads();
  }
#pragma unroll
  for (int ii = 0; ii < 4; ii++) {
    const int o = o0 + ty * 4 + ii;
    const float bias = b2[o];
    float4 r;
    r.x = fmaxf(acc[ii][0] + bias, 0.0f);
    r.y = fmaxf(acc[ii][1] + bias, 0.0f);
    r.z = fmaxf(acc[ii][2] + bias, 0.0f);
    r.w = fmaxf(acc[ii][3] + bias, 0.0f);
    *(float4*)&g_H2[(size_t)o * M_GRID + m0 + tx * 4] = r;
  }
}

// ---------------- Layer-3 GEMM (odd rows of W3) + param processing -> g_table
__global__ __launch_bounds__(256) void k_gemm3proc(const float* __restrict__ W3,
                                                   const float* __restrict__ b3) {
  __shared__ float Wt[64][68];
  __shared__ float Ht[64][68];
  __shared__ float raws[64][65];  // [p][m]
  const int t = threadIdx.x;
  const int m0 = blockIdx.x * 64;
  const int ty = t >> 4, tx = t & 15;
  float acc[4][4] = {};
  for (int kc = 0; kc < 256; kc += 64) {
    {
      const int p = t >> 2, seg = t & 3;
      const int row = (p < 63) ? (2 * p + 1) : 1;
      const float* src = W3 + (size_t)row * 256 + kc + seg * 16;
#pragma unroll
      for (int q = 0; q < 4; q++) {
        float4 v = *(const float4*)(src + 4 * q);
        int k = seg * 16 + 4 * q;
        Wt[k + 0][p] = v.x; Wt[k + 1][p] = v.y;
        Wt[k + 2][p] = v.z; Wt[k + 3][p] = v.w;
      }
    }
    {
      const int k = t & 63, mseg = (t >> 6) * 16;
      const float* src = g_H2 + (size_t)(kc + k) * M_GRID + m0 + mseg;
#pragma unroll
      for (int q = 0; q < 4; q++) {
        float4 v = *(const float4*)(src + 4 * q);
        *(float4*)&Ht[k][mseg + 4 * q] = v;
      }
    }
    __syncthreads();
#pragma unroll
    for (int k = 0; k < 64; k++) {
      float4 av = *(const float4*)&Wt[k][ty * 4];
      float4 bv = *(const float4*)&Ht[k][tx * 4];
      acc[0][0] = fmaf(av.x, bv.x, acc[0][0]); acc[0][1] = fmaf(av.x, bv.y, acc[0][1]);
      acc[0][2] = fmaf(av.x, bv.z, acc[0][2]); acc[0][3] = fmaf(av.x, bv.w, acc[0][3]);
      acc[1][0] = fmaf(av.y, bv.x, acc[1][0]); acc[1][1] = fmaf(av.y, bv.y, acc[1][1]);
      acc[1][2] = fmaf(av.y, bv.z, acc[1][2]); acc[1][3] = fmaf(av.y, bv.w, acc[1][3]);
      acc[2][0] = fmaf(av.z, bv.x, acc[2][0]); acc[2][1] = fmaf(av.z, bv.y, acc[2][1]);
      acc[2][2] = fmaf(av.z, bv.z, acc[2][2]); acc[2][3] = fmaf(av.z, bv.w, acc[2][3]);
      acc[3][0] = fmaf(av.w, bv.x, acc[3][0]); acc[3][1] = fmaf(av.w, bv.y, acc[3][1]);
      acc[3][2] = fmaf(av.w, bv.z, acc[3][2]); acc[3][3] = fmaf(av.w, bv.w, acc[3][3]);
    }
    __syncthreads();
  }
#pragma unroll
  for (int ii = 0; ii < 4; ii++) {
    const int p = ty * 4 + ii;
    const int bi = (p < 63) ? (2 * p + 1) : 1;
    const float bias = b3[bi];
    raws[p][tx * 4 + 0] = acc[ii][0] + bias;
    raws[p][tx * 4 + 1] = acc[ii][1] + bias;
    raws[p][tx * 4 + 2] = acc[ii][2] + bias;
    raws[p][tx * 4 + 3] = acc[ii][3] + bias;
  }
  __syncthreads();
  if (t < 64) process_column(&raws[0][t], 65, g_table + (size_t)(m0 + t) * REC);
  if (t == 64 && blockIdx.x == 0) process_column(b3, 2, g_knots0);  // dim-0 constant knots
}

// ---------------- Main flow kernel: 4 steps per sample
__global__ __launch_bounds__(256) void k_main(const float* __restrict__ x,
                                              float* __restrict__ out) {
  __shared__ float kn0[REC];
  for (int j = threadIdx.x; j < REC; j += 256) kn0[j] = g_knots0[j];
  __syncthreads();
  const int i = blockIdx.x * 256 + threadIdx.x;
  const float2 xv = ((const float2*)x)[i];
  float z0 = xv.x, z1 = xv.y;
  ((float2*)out)[i] = xv;  // step 0 = input
  for (int t = 0; t < 4; t++) {
    // ---- dim 1: table lookup keyed by u = current z0 ----
    float tt = (z0 - U_LO) * INV_DELTA;
    int i0 = (int)floorf(tt);
    i0 = min(max(i0, 0), M_GRID - 2);
    float f = fminf(fmaxf(tt - (float)i0, 0.0f), 1.0f);
    const float* r0 = g_table + (size_t)i0 * REC;
    const float* r1 = r0 + REC;
    float cwv[17];
#pragma unroll
    for (int q = 0; q < 4; q++) {
      float4 a = *(const float4*)(r0 + 4 * q);
      float4 b = *(const float4*)(r1 + 4 * q);
      cwv[4 * q + 0] = fmaf(f, b.x - a.x, a.x);
      cwv[4 * q + 1] = fmaf(f, b.y - a.y, a.y);
      cwv[4 * q + 2] = fmaf(f, b.z - a.z, a.z);
      cwv[4 * q + 3] = fmaf(f, b.w - a.w, a.w);
    }
    cwv[16] = 5.0f;  // exact in every record
    float xc1 = fminf(fmaxf(z1, -5.0f), 5.0f);
    int k1 = -1;
    float xk = cwv[0], xk1 = cwv[16];
    bool seen = false;
#pragma unroll
    for (int j = 0; j < 16; j++) {
      bool c = xc1 >= cwv[j];
      k1 += c ? 1 : 0;
      xk = c ? cwv[j] : xk;
      bool ff = (!c) && (!seen);
      xk1 = ff ? cwv[j] : xk1;
      seen = seen || (!c);
    }
    const float* s0 = r0 + 20 + 8 * k1;
    const float* s1 = s0 + REC;
    float4 pa = *(const float4*)s0;
    float4 pb = *(const float4*)s1;
    float la = s0[4], lb = s1[4];
    float yk  = fmaf(f, pb.x - pa.x, pa.x);
    float yk1 = fmaf(f, pb.y - pa.y, pa.y);
    float dk  = fmaf(f, pb.z - pa.z, pa.z);
    float dk1 = fmaf(f, pb.w - pa.w, pa.w);
    float lam = fmaf(f, lb - la, la);
    float z1n = spline_eval(z1, xk, xk1, yk, yk1, dk, dk1, lam);
    // ---- dim 0: constant knots from LDS ----
    float xc0 = fminf(fmaxf(z0, -5.0f), 5.0f);
    int k0 = -1;
    float xk0 = kn0[0], xk01 = kn0[16];
    bool seen0 = false;
#pragma unroll
    for (int j = 0; j < 16; j++) {
      float cj = kn0[j];
      bool c = xc0 >= cj;
      k0 += c ? 1 : 0;
      xk0 = c ? cj : xk0;
      bool ff = (!c) && (!seen0);
      xk01 = ff ? cj : xk01;
      seen0 = seen0 || (!c);
    }
    const int sb = 20 + 8 * k0;
    float z0n = spline_eval(z0, xk0, xk01, kn0[sb], kn0[sb + 1],
                            kn0[sb + 2], kn0[sb + 3], kn0[sb + 4]);
    z0 = z0n; z1 = z1n;
    ((float2*)(out + (size_t)(t + 1) * (N_SAMPLES * 2)))[i] = make_float2(z0, z1);
  }
}

extern "C" void kernel_launch(void* const* d_in, const int* in_sizes, int n_in,
                              void* d_out, int out_size, void* d_ws, size_t ws_size,
                              hipStream_t stream) {
  const float* x  = (const float*)d_in[0];
  const float* W1 = (const float*)d_in[1];
  const float* b1 = (const float*)d_in[2];
  const float* W2 = (const float*)d_in[3];
  const float* b2 = (const float*)d_in[4];
  const float* W3 = (const float*)d_in[5];
  const float* b3 = (const float*)d_in[6];
  float* out = (float*)d_out;
  hipLaunchKernelGGL(k_gemm2, dim3(M_GRID / 64, 4), dim3(256), 0, stream, W1, b1, W2, b2);
  hipLaunchKernelGGL(k_gemm3proc, dim3(M_GRID / 64), dim3(256), 0, stream, W3, b3);
  hipLaunchKernelGGL(k_main, dim3(N_SAMPLES / 256), dim3(256), 0, stream, x, out);
}